// Round 15
// baseline (151.250 us; speedup 1.0000x reference)
//
#include <hip/hip_runtime.h>
#include <hip/hip_bf16.h>

typedef __bf16 bf16x8 __attribute__((ext_vector_type(8)));
typedef float f32x4 __attribute__((ext_vector_type(4)));
typedef float f32x16 __attribute__((ext_vector_type(16)));
typedef unsigned int uint2v __attribute__((ext_vector_type(2)));

#define MFMA16 __builtin_amdgcn_mfma_f32_16x16x32_bf16
#define MFMA32 __builtin_amdgcn_mfma_f32_32x32x16_bf16

__device__ __forceinline__ unsigned short f2b(float f) {
  unsigned int u = __float_as_uint(f);
  u += 0x7FFFu + ((u >> 16) & 1u);
  return (unsigned short)(u >> 16);
}

__device__ __forceinline__ float b2f(unsigned short s) {
  return __uint_as_float(((unsigned)s) << 16);
}

union U128 {
  uint4 u;
  unsigned short s[8];
  bf16x8 b;
};

union BPack {
  __hip_bfloat162 h2;
  unsigned u;
};

__device__ __forceinline__ unsigned packbf(float a, float b) {
  BPack p;
  p.h2 = __float22bfloat162_rn(make_float2(a, b));
  return p.u;
}

// device-scope grid barrier (all 512 blocks guaranteed co-resident:
// grid 512 x launch_bounds(256,2) = exactly 2 blocks/CU x 256 CUs).
// release fence (L2 wb) -> device-scope atomic arrive -> spin on
// agent-scope load -> acquire fence (L2 inv). Spin guard (2^27) turns
// any residency pathology into a wrong-answer fail instead of a hang.
__device__ __forceinline__ void grid_barrier(unsigned* bar, unsigned nblk) {
  __syncthreads();
  if (threadIdx.x == 0) {
    __threadfence();                 // agent release: prior stores visible
    atomicAdd(bar, 1u);              // device-scope by default (m20)
    unsigned v;
    int guard = 0;
    do {
      v = __hip_atomic_load(bar, __ATOMIC_RELAXED, __HIP_MEMORY_SCOPE_AGENT);
    } while (v < nblk && ++guard < (1 << 27));
    __threadfence();                 // agent acquire: see others' stores
  }
  __syncthreads();
}

// ---------------- fused projection + flash attention ----------------------
// R22 = R21's fusion with a GRAPH-SAFE barrier. R21's
// hipLaunchCooperativeKernel was silently rejected under the harness's
// graph capture (out stayed zeroed -> absmax 5.375 = max|ref|). Same body:
// Phase 1 = R11 proj (blockIdx -> (b = blk&7, n-tile)); grid_barrier;
// Phase 2 = R20 attn (blockIdx -> (b, m64-tile)); b = blk&7 both phases
// keeps batch->XCD pinning. Removes one kernel launch + stream gap
// (~10 us theory). LDS = union of phase buffers (31.2 KB, phases
// temporally disjoint). attn loop byte-identical to R20 (101.2 us best).
__global__ __launch_bounds__(256, 2) void fused_kernel(
    const float* __restrict__ x, const float* __restrict__ wq,
    const float* __restrict__ wk, const float* __restrict__ wv_w,
    unsigned short* __restrict__ f_t, unsigned short* __restrict__ g_t,
    unsigned short* __restrict__ h, const float* __restrict__ gamma,
    float* __restrict__ out, unsigned* __restrict__ bar) {
  __shared__ union SMem {
    struct {
      unsigned short xT[64 * 64];
      unsigned short wT[96 * 72];
      unsigned short hT[64 * 72];
    } p;  // 31.2 KB (projection phase)
    struct {
      unsigned short Opart[4][32][66];
      float lred[4][64];
      float lsum[64];
    } a;  // 18.2 KB (attention epilogue)
  } sm;

  const int tid = (int)threadIdx.x;
  const int b = (int)blockIdx.x & 7;
  const int t64 = (int)blockIdx.x >> 3;  // 64-wide tile index (n0 / m0)

  // ===================== phase 1: projection =====================
  {
    const int wvp = tid >> 6;
    const int lane = tid & 63;
    const int n0 = t64 << 6;

    // ---- stage xT: thread loads 16 c's for n=lane, packs, swizzled ----
    {
      const float* xb = x + ((size_t)b << 18) + n0 + lane;
      const int c0 = wvp * 16;
      float xv[16];
#pragma unroll
      for (int cc = 0; cc < 16; ++cc) xv[cc] = xb[(size_t)(c0 + cc) << 12];
#pragma unroll
      for (int p = 0; p < 4; ++p) {
        const int c = c0 + 4 * p;
        uint2 d;
        d.x = packbf(xv[4 * p + 0], xv[4 * p + 1]);
        d.y = packbf(xv[4 * p + 2], xv[4 * p + 3]);
        const int g = c >> 3;
        const int idx =
            lane * 64 + (((g ^ (lane & 7)) << 3) | (((c >> 2) & 1) << 2));
        *(uint2*)&sm.p.xT[idx] = d;
      }
    }
    // ---- stage wT (80 rows of 64, bf16); wq scaled by log2(e) ----
#pragma unroll
    for (int i = 0; i < 20; ++i) {
      const int idx = i * 256 + tid;
      const float wval = (idx < 512) ? wq[idx] * 1.44269504f
                       : (idx < 1024) ? wk[idx - 512]
                                      : wv_w[idx - 1024];
      sm.p.wT[(idx >> 6) * 72 + (idx & 63)] = f2b(wval);
    }
    __syncthreads();

    const int t = lane & 15, q = lane >> 4;
    const int nloc = wvp * 16 + t;
    U128 Bf[2];
#pragma unroll
    for (int kp = 0; kp < 2; ++kp) {
      const int g = kp * 4 + q;
      Bf[kp].u = *(const uint4*)&sm.p.xT[nloc * 64 + ((g ^ (nloc & 7)) << 3)];
    }
    const int nabs = n0 + nloc;

    // rt = 0: f (r0-7) / g (r8-15): one packed 8 B store per thread.
    {
      f32x4 acc = {0.f, 0.f, 0.f, 0.f};
#pragma unroll
      for (int kp = 0; kp < 2; ++kp) {
        U128 Af;
        Af.u = *(const uint4*)&sm.p.wT[t * 72 + ((kp * 4 + q) << 3)];
        acc = MFMA16(Af.b, Bf[kp].b, acc, 0, 0, 0);
      }
      uint2 d;
      d.x = packbf(acc[0], acc[1]);
      d.y = packbf(acc[2], acc[3]);
      unsigned short* dst = (q & 2) ? g_t : f_t;
      *(uint2*)&dst[((size_t)((b << 12) + nabs) << 3) + ((q & 1) << 2)] = d;
    }
    // rt = 1..4: h rows -> LDS, transposed packed readback below.
#pragma unroll
    for (int rt = 1; rt < 5; ++rt) {
      f32x4 acc = {0.f, 0.f, 0.f, 0.f};
#pragma unroll
      for (int kp = 0; kp < 2; ++kp) {
        U128 Af;
        Af.u = *(const uint4*)&sm.p.wT[(rt * 16 + t) * 72 + ((kp * 4 + q) << 3)];
        acc = MFMA16(Af.b, Bf[kp].b, acc, 0, 0, 0);
      }
      const int cbase = (rt - 1) * 16 + 4 * q;
#pragma unroll
      for (int reg = 0; reg < 4; ++reg)
        sm.p.hT[(cbase + reg) * 72 + nloc] = f2b(acc[reg]);
    }
    __syncthreads();

    // packed h store: thread owns row c = tid&63, n-quarter = tid>>6.
    {
      const int hc = tid & 63;
      const int hw = tid >> 6;
      const uint4 v0 = *(const uint4*)&sm.p.hT[hc * 72 + hw * 16];
      const uint4 v1 = *(const uint4*)&sm.p.hT[hc * 72 + hw * 16 + 8];
      const size_t hbase =
          ((size_t)b << 18) + ((size_t)((n0 + hw * 16) >> 3) << 9) + (hc << 3);
      *(uint4*)&h[hbase] = v0;
      *(uint4*)&h[hbase + 512] = v1;
    }
  }

  // grid-wide barrier: all proj writes visible device-wide before attn reads
  grid_barrier(bar, (unsigned)gridDim.x);

  // ===================== phase 2: attention =====================
  {
    const int wave = tid >> 6;
    const int lane = tid & 63;
    const int ml = lane & 31;
    const int hh = lane >> 5;
    const int m0 = t64 << 6;  // m64 tile base

    const unsigned short* fb = f_t + ((size_t)b << 15);
    const unsigned short* hb = h + ((size_t)b << 18);  // blocked layout

    U128 G0, G1;
    G0.u = make_uint4(0u, 0u, 0u, 0u);
    G1.u = make_uint4(0u, 0u, 0u, 0u);
    if (hh == 0) {
      G0.u = *(const uint4*)(g_t + ((size_t)((b << 12) + m0 + ml) << 3));
      G1.u = *(const uint4*)(g_t + ((size_t)((b << 12) + m0 + 32 + ml) << 3));
    }

    f32x16 O00 = {}, O01 = {}, O10 = {}, O11 = {};
    float2 lp0v = make_float2(0.f, 0.f), lp1v = make_float2(0.f, 0.f);
    const f32x16 ZC = {};

    const int nbase = wave << 10;  // n-quarter per wave (1024 n = 32 tiles)

    const unsigned short* fp = fb + ((size_t)(nbase + ml) << 3);
    const unsigned short* hp =
        hb + ((nbase >> 3) << 9) + (hh << 9) + (ml << 3);

    // fragment slots: F ping-pong (2), H ping-pong (2x4), TWO in-place S
    U128 F0, F1, Ha_e[4], Ha_o[4];
    f32x16 S0, S1;

    // prologue: F tiles 0,1; H tile 0; S0/S1 = scores(tile 0)
    F0.u = *(const uint4*)(fp);
    F1.u = *(const uint4*)(fp + 256);
    Ha_e[0].u = *(const uint4*)(hp);
    Ha_e[1].u = *(const uint4*)(hp + 256);
    Ha_e[2].u = *(const uint4*)(hp + 1024);
    Ha_e[3].u = *(const uint4*)(hp + 1280);
    S0 = MFMA32(F0.b, G0.b, ZC, 0, 0, 0);
    S1 = MFMA32(F0.b, G1.b, ZC, 0, 0, 0);

    // half: exps consume S (tile k); if produce, S <- scores(k+1) in place;
    // pack + PV into this m-tile's O pair using shared H fragments.
    auto half = [&](f32x16& S, const U128& G, float2& lp, f32x16& Oa,
                    f32x16& Ob, const U128* Hv, const U128& Fn, bool produce) {
      float e[16];
#pragma unroll
      for (int r = 0; r < 16; ++r) e[r] = __builtin_amdgcn_exp2f(S[r]);
      if (produce) S = MFMA32(Fn.b, G.b, ZC, 0, 0, 0);
      lp.x +=
          ((e[0] + e[2]) + (e[4] + e[6])) + ((e[8] + e[10]) + (e[12] + e[14]));
      lp.y +=
          ((e[1] + e[3]) + (e[5] + e[7])) + ((e[9] + e[11]) + (e[13] + e[15]));
#pragma unroll
      for (int kt = 0; kt < 2; ++kt) {
        const unsigned A0 = packbf(e[8 * kt + 0], e[8 * kt + 1]);
        const unsigned A1 = packbf(e[8 * kt + 2], e[8 * kt + 3]);
        const unsigned B0 = packbf(e[8 * kt + 4], e[8 * kt + 5]);
        const unsigned B1 = packbf(e[8 * kt + 6], e[8 * kt + 7]);
        const uint2v r0 = __builtin_amdgcn_permlane32_swap(A0, B0, false, false);
        const uint2v r1 = __builtin_amdgcn_permlane32_swap(A1, B1, false, false);
        U128 P;
        P.u.x = r0[0];
        P.u.y = r1[0];
        P.u.z = r0[1];
        P.u.w = r1[1];
        Oa = MFMA32(Hv[2 * kt + 0].b, P.b, Oa, 0, 0, 0);
        Ob = MFMA32(Hv[2 * kt + 1].b, P.b, Ob, 0, 0, 0);
      }
    };
    auto body = [&](const U128* Hv, const U128& Fn, bool produce) {
      half(S0, G0, lp0v, O00, O01, Hv, Fn, produce);
      half(S1, G1, lp1v, O10, O11, Hv, Fn, produce);
    };

    // main loop: tiles 2j, 2j+1 for j=0..14; tiles 30,31 peeled.
    // hp bumped MID-iteration: all H offsets <= 6656 B (imm-foldable).
#pragma unroll 1
    for (int j = 0; j < 15; ++j) {
      Ha_o[0].u = *(const uint4*)(hp + 2048);
      Ha_o[1].u = *(const uint4*)(hp + 2304);
      Ha_o[2].u = *(const uint4*)(hp + 3072);
      Ha_o[3].u = *(const uint4*)(hp + 3328);
      F0.u = *(const uint4*)(fp + 512);
      body(Ha_e, F1, true);                   // tile 2j
      hp += 4096;
      Ha_e[0].u = *(const uint4*)(hp);
      Ha_e[1].u = *(const uint4*)(hp + 256);
      Ha_e[2].u = *(const uint4*)(hp + 1024);
      Ha_e[3].u = *(const uint4*)(hp + 1280);
      F1.u = *(const uint4*)(fp + 768);
      body(Ha_o, F0, true);                   // tile 2j+1
      fp += 512;
    }
    // tail: hp = base of tile 30; Ha_e holds H(30), F1 holds F(31)
    Ha_o[0].u = *(const uint4*)(hp + 2048);
    Ha_o[1].u = *(const uint4*)(hp + 2304);
    Ha_o[2].u = *(const uint4*)(hp + 3072);
    Ha_o[3].u = *(const uint4*)(hp + 3328);
    body(Ha_e, F1, true);                     // tile 30
    body(Ha_o, F1, false);                    // tile 31 (no produce)

    // ---- epilogue: 2 phases (tile0 = O00/O01, tile1 = O10/O11) ----
    float lp0 = lp0v.x + lp0v.y;
    float lp1 = lp1v.x + lp1v.y;
    lp0 += __shfl_xor(lp0, 32, 64);
    lp1 += __shfl_xor(lp1, 32, 64);

    __syncthreads();  // proj-phase LDS fully dead before alias reuse
    if (hh == 0) {
      sm.a.lred[wave][ml] = lp0;
      sm.a.lred[wave][32 + ml] = lp1;
    }

    const float gam = gamma[0];

    auto stash = [&](const f32x16& Oa, const f32x16& Ob) {
#pragma unroll
      for (int r = 0; r < 8; ++r) {
        const int c0 = ((2 * r) & 3) + 8 * (r >> 1) + 4 * hh;
        *(unsigned*)&sm.a.Opart[wave][ml][c0] = packbf(Oa[2 * r], Oa[2 * r + 1]);
        *(unsigned*)&sm.a.Opart[wave][ml][c0 + 32] =
            packbf(Ob[2 * r], Ob[2 * r + 1]);
      }
    };
    auto drain = [&](int p) {
      const int c = tid >> 2;
      const int m8 = (tid & 3) << 3;
      float a[8];
#pragma unroll
      for (int j = 0; j < 8; ++j) a[j] = 0.f;
#pragma unroll
      for (int w = 0; w < 4; ++w)
#pragma unroll
        for (int j = 0; j < 8; ++j) a[j] += b2f(sm.a.Opart[w][m8 + j][c]);
      const f32x4 l0 = *(const f32x4*)&sm.a.lsum[p * 32 + m8];
      const f32x4 l1 = *(const f32x4*)&sm.a.lsum[p * 32 + m8 + 4];
      const size_t oi = (((size_t)b * 64 + c) << 12) + m0 + p * 32 + m8;
      f32x4 xo0 = *(const f32x4*)(x + oi);
      f32x4 xo1 = *(const f32x4*)(x + oi + 4);
#pragma unroll
      for (int j = 0; j < 4; ++j) {
        xo0[j] += gam / l0[j] * a[j];
        xo1[j] += gam / l1[j] * a[j + 4];
      }
      *(f32x4*)(out + oi) = xo0;
      *(f32x4*)(out + oi + 4) = xo1;
    };

    stash(O00, O01);
    __syncthreads();  // lred + phase-0 Opart visible
    if (tid < 64)
      sm.a.lsum[tid] = (sm.a.lred[0][tid] + sm.a.lred[1][tid]) +
                       (sm.a.lred[2][tid] + sm.a.lred[3][tid]);
    __syncthreads();  // lsum visible
    drain(0);
    __syncthreads();  // phase-0 reads done before overwrite
    stash(O10, O11);
    __syncthreads();  // phase-1 Opart visible
    drain(1);
  }
}

extern "C" void kernel_launch(void* const* d_in, const int* in_sizes, int n_in,
                              void* d_out, int out_size, void* d_ws, size_t ws_size,
                              hipStream_t stream) {
  (void)in_sizes; (void)n_in; (void)out_size; (void)ws_size;
  const float* x = (const float*)d_in[0];
  const float* wq = (const float*)d_in[1];
  const float* wk = (const float*)d_in[2];
  const float* wv = (const float*)d_in[3];
  const float* gamma = (const float*)d_in[4];
  float* out = (float*)d_out;

  // workspace: f_t [8][4096][8] bf16, g_t same, h_blk [8][512][64][8] bf16,
  // then the grid-barrier counter (zeroed each launch; ws is poisoned
  // between iterations by the harness).
  unsigned short* f_t = (unsigned short*)d_ws;
  unsigned short* g_t = f_t + (size_t)8 * 4096 * 8;
  unsigned short* h = g_t + (size_t)8 * 4096 * 8;
  unsigned* bar = (unsigned*)(h + (size_t)8 * 512 * 64 * 8);

  hipMemsetAsync(bar, 0, 16, stream);  // graph-capturable (harness uses it)
  fused_kernel<<<512, 256, 0, stream>>>(x, wq, wk, wv, f_t, g_t, h, gamma,
                                        out, bar);
}

// Round 16
// 99.807 us; speedup vs baseline: 1.5154x; 1.5154x over previous
//
#include <hip/hip_runtime.h>
#include <hip/hip_bf16.h>

typedef __bf16 bf16x8 __attribute__((ext_vector_type(8)));
typedef float f32x4 __attribute__((ext_vector_type(4)));
typedef float f32x16 __attribute__((ext_vector_type(16)));
typedef unsigned int uint2v __attribute__((ext_vector_type(2)));

#define MFMA16 __builtin_amdgcn_mfma_f32_16x16x32_bf16
#define MFMA32 __builtin_amdgcn_mfma_f32_32x32x16_bf16

__device__ __forceinline__ unsigned short f2b(float f) {
  unsigned int u = __float_as_uint(f);
  u += 0x7FFFu + ((u >> 16) & 1u);
  return (unsigned short)(u >> 16);
}

__device__ __forceinline__ float b2f(unsigned short s) {
  return __uint_as_float(((unsigned)s) << 16);
}

union U128 {
  uint4 u;
  unsigned short s[8];
  bf16x8 b;
};

union BPack {
  __hip_bfloat162 h2;
  unsigned u;
};

__device__ __forceinline__ unsigned packbf(float a, float b) {
  BPack p;
  p.h2 = __float22bfloat162_rn(make_float2(a, b));
  return p.u;
}

// ---------------- projection via MFMA ----------------
// grid 512 = (b = blk&7, n0 = 64-tile). block 256 (4 waves).
// Y[96 pad][4096] = W[96x64] X[64x4096] per batch, bf16 MFMA 16x16x32.
// wq rows pre-scaled by log2(e) so attention uses native exp2.
// h stored BLOCKED: h_blk[b][n>>3][c][n&7].
// R11: packed stores (f/g one 8 B store; h bounced via LDS, 2x16 B stores).
// SESSION FINAL NOTE: fusion with attn is REFUTED on this harness —
// cooperative launch is silently rejected under graph capture (R21), and a
// manual device-scope spin barrier costs ~35-40 us >> the ~8-10 us launch
// gap it saves (R22, 92 us fused vs ~52 us separate).
__global__ __launch_bounds__(256, 2) void proj_kernel(
    const float* __restrict__ x, const float* __restrict__ wq,
    const float* __restrict__ wk, const float* __restrict__ wv_w,
    unsigned short* __restrict__ f_t, unsigned short* __restrict__ g_t,
    unsigned short* __restrict__ h_out) {
  __shared__ unsigned short xT[64 * 64];
  __shared__ unsigned short wT[96 * 72];
  __shared__ unsigned short hT[64 * 72];  // [c][n], pad 72 (16B-aligned rows)

  const int tid = (int)threadIdx.x;
  const int wvp = tid >> 6;
  const int lane = tid & 63;
  const int b = (int)blockIdx.x & 7;
  const int n0 = ((int)blockIdx.x >> 3) << 6;

  // ---- stage xT: thread loads 16 c's for n=lane, packs, swizzled write ----
  {
    const float* xb = x + ((size_t)b << 18) + n0 + lane;
    const int c0 = wvp * 16;
    float xv[16];
#pragma unroll
    for (int cc = 0; cc < 16; ++cc) xv[cc] = xb[(size_t)(c0 + cc) << 12];
#pragma unroll
    for (int p = 0; p < 4; ++p) {
      const int c = c0 + 4 * p;
      uint2 d;
      d.x = packbf(xv[4 * p + 0], xv[4 * p + 1]);
      d.y = packbf(xv[4 * p + 2], xv[4 * p + 3]);
      const int g = c >> 3;
      const int idx = lane * 64 + (((g ^ (lane & 7)) << 3) | (((c >> 2) & 1) << 2));
      *(uint2*)&xT[idx] = d;
    }
  }
  // ---- stage wT (80 rows of 64, bf16); wq scaled by log2(e) ----
#pragma unroll
  for (int i = 0; i < 20; ++i) {
    const int idx = i * 256 + tid;
    const float wval = (idx < 512) ? wq[idx] * 1.44269504f
                     : (idx < 1024) ? wk[idx - 512]
                                    : wv_w[idx - 1024];
    wT[(idx >> 6) * 72 + (idx & 63)] = f2b(wval);
  }
  __syncthreads();

  // ---- compute ----
  const int t = lane & 15, q = lane >> 4;
  const int nloc = wvp * 16 + t;
  U128 Bf[2];
#pragma unroll
  for (int kp = 0; kp < 2; ++kp) {
    const int g = kp * 4 + q;
    Bf[kp].u = *(const uint4*)&xT[nloc * 64 + ((g ^ (nloc & 7)) << 3)];
  }
  const int nabs = n0 + nloc;

  // rt = 0: f (r0-7) / g (r8-15): one packed 8 B store per thread.
  {
    f32x4 acc = {0.f, 0.f, 0.f, 0.f};
#pragma unroll
    for (int kp = 0; kp < 2; ++kp) {
      U128 Af;
      Af.u = *(const uint4*)&wT[t * 72 + ((kp * 4 + q) << 3)];
      acc = MFMA16(Af.b, Bf[kp].b, acc, 0, 0, 0);
    }
    uint2 d;
    d.x = packbf(acc[0], acc[1]);
    d.y = packbf(acc[2], acc[3]);
    unsigned short* dst = (q & 2) ? g_t : f_t;
    *(uint2*)&dst[((size_t)((b << 12) + nabs) << 3) + ((q & 1) << 2)] = d;
  }
  // rt = 1..4: h rows -> LDS, transposed packed readback below.
#pragma unroll
  for (int rt = 1; rt < 5; ++rt) {
    f32x4 acc = {0.f, 0.f, 0.f, 0.f};
#pragma unroll
    for (int kp = 0; kp < 2; ++kp) {
      U128 Af;
      Af.u = *(const uint4*)&wT[(rt * 16 + t) * 72 + ((kp * 4 + q) << 3)];
      acc = MFMA16(Af.b, Bf[kp].b, acc, 0, 0, 0);
    }
    const int cbase = (rt - 1) * 16 + 4 * q;
#pragma unroll
    for (int reg = 0; reg < 4; ++reg)
      hT[(cbase + reg) * 72 + nloc] = f2b(acc[reg]);
  }
  __syncthreads();

  // packed h store: thread owns row c = tid&63, n-quarter = tid>>6.
  {
    const int hc = tid & 63;
    const int hw = tid >> 6;
    const uint4 v0 = *(const uint4*)&hT[hc * 72 + hw * 16];
    const uint4 v1 = *(const uint4*)&hT[hc * 72 + hw * 16 + 8];
    const size_t hbase =
        ((size_t)b << 18) + ((size_t)((n0 + hw * 16) >> 3) << 9) + (hc << 3);
    *(uint4*)&h_out[hbase] = v0;
    *(uint4*)&h_out[hbase + 512] = v1;
  }
}

// ---------------- flash attention ------------------------------------------
// R23 = R20 RESTORED (session best, 101.2 us): grid 512, 256 thr, 4 indep
// waves, m64/ILP2, H ping-pong, in-place S pipeline, imm-foldable offsets,
// float2 lp, NO setprio (R19: removal neutral-to-positive, m190 prior),
// 2-phase epilogue.
// attn floor (~40 us, 20% MfmaUtil / 50% VALUBusy / 4% HBM / 0 conflicts)
// survived 13 structural attacks: reg prefetch at any depth spills
// (R9/R13/R15/R17 — unified RF, working set at the 256-reg edge); LDS
// staging slower (R18); 16 waves/CU hurts (R14); ILP<->occupancy swap
// neutral (R12); score-MFMA pipelining neutral (R10); VALU diet neutral
// (R16); epilogue restructure neutral (R20); fusion refuted (R21/R22).
// Remaining stall is unattributable without offline disasm.
__global__ __launch_bounds__(256, 2) void attn_kernel(
    const unsigned short* __restrict__ f_t, const unsigned short* __restrict__ g_t,
    const unsigned short* __restrict__ h, const float* __restrict__ x,
    const float* __restrict__ gamma, float* __restrict__ out) {
  __shared__ unsigned short Opart[4][32][66];  // [wave][m][c], 16.9 KB
  __shared__ float lred[4][64];
  __shared__ float lsum[64];

  const int tid = (int)threadIdx.x;
  const int wave = tid >> 6;
  const int lane = tid & 63;
  const int ml = lane & 31;
  const int hh = lane >> 5;

  const int b = (int)blockIdx.x & 7;
  const int m0 = ((int)blockIdx.x >> 3) << 6;  // m64 tile base

  const unsigned short* fb = f_t + ((size_t)b << 15);
  const unsigned short* hb = h + ((size_t)b << 18);  // blocked layout

  U128 G0, G1;
  G0.u = make_uint4(0u, 0u, 0u, 0u);
  G1.u = make_uint4(0u, 0u, 0u, 0u);
  if (hh == 0) {
    G0.u = *(const uint4*)(g_t + ((size_t)((b << 12) + m0 + ml) << 3));
    G1.u = *(const uint4*)(g_t + ((size_t)((b << 12) + m0 + 32 + ml) << 3));
  }

  f32x16 O00 = {}, O01 = {}, O10 = {}, O11 = {};
  float2 lp0v = make_float2(0.f, 0.f), lp1v = make_float2(0.f, 0.f);
  const f32x16 ZC = {};

  const int nbase = wave << 10;  // n-quarter per wave (1024 n = 32 tiles)

  const unsigned short* fp = fb + ((size_t)(nbase + ml) << 3);
  const unsigned short* hp = hb + ((nbase >> 3) << 9) + (hh << 9) + (ml << 3);

  // fragment slots: F ping-pong (2), H ping-pong (2x4), TWO in-place S
  U128 F0, F1, Ha_e[4], Ha_o[4];
  f32x16 S0, S1;

  // prologue: F tiles 0,1; H tile 0; S0/S1 = scores(tile 0)
  F0.u = *(const uint4*)(fp);
  F1.u = *(const uint4*)(fp + 256);
  Ha_e[0].u = *(const uint4*)(hp);
  Ha_e[1].u = *(const uint4*)(hp + 256);
  Ha_e[2].u = *(const uint4*)(hp + 1024);
  Ha_e[3].u = *(const uint4*)(hp + 1280);
  S0 = MFMA32(F0.b, G0.b, ZC, 0, 0, 0);
  S1 = MFMA32(F0.b, G1.b, ZC, 0, 0, 0);

  // half: exps consume S (tile k, this G); if produce, S <- scores(k+1)
  // in place; pack + PV into this m-tile's O pair using shared H fragments.
  auto half = [&](f32x16& S, const U128& G, float2& lp, f32x16& Oa, f32x16& Ob,
                  const U128* Hv, const U128& Fn, bool produce) {
    float e[16];
#pragma unroll
    for (int r = 0; r < 16; ++r) e[r] = __builtin_amdgcn_exp2f(S[r]);
    if (produce) S = MFMA32(Fn.b, G.b, ZC, 0, 0, 0);
    // denominator partial: even/odd split -> paired adds, depth-3 trees
    lp.x += ((e[0] + e[2]) + (e[4] + e[6])) + ((e[8] + e[10]) + (e[12] + e[14]));
    lp.y += ((e[1] + e[3]) + (e[5] + e[7])) + ((e[9] + e[11]) + (e[13] + e[15]));
#pragma unroll
    for (int kt = 0; kt < 2; ++kt) {
      const unsigned A0 = packbf(e[8 * kt + 0], e[8 * kt + 1]);
      const unsigned A1 = packbf(e[8 * kt + 2], e[8 * kt + 3]);
      const unsigned B0 = packbf(e[8 * kt + 4], e[8 * kt + 5]);
      const unsigned B1 = packbf(e[8 * kt + 6], e[8 * kt + 7]);
      const uint2v r0 = __builtin_amdgcn_permlane32_swap(A0, B0, false, false);
      const uint2v r1 = __builtin_amdgcn_permlane32_swap(A1, B1, false, false);
      U128 P;
      P.u.x = r0[0];
      P.u.y = r1[0];
      P.u.z = r0[1];
      P.u.w = r1[1];
      Oa = MFMA32(Hv[2 * kt + 0].b, P.b, Oa, 0, 0, 0);
      Ob = MFMA32(Hv[2 * kt + 1].b, P.b, Ob, 0, 0, 0);
    }
  };
  auto body = [&](const U128* Hv, const U128& Fn, bool produce) {
    half(S0, G0, lp0v, O00, O01, Hv, Fn, produce);
    half(S1, G1, lp1v, O10, O11, Hv, Fn, produce);
  };

  // main loop: tiles 2j, 2j+1 for j=0..14; tiles 30,31 peeled.
  // hp bumped MID-iteration: all H-load offsets stay <= 6656 B (imm-foldable).
#pragma unroll 1
  for (int j = 0; j < 15; ++j) {
    Ha_o[0].u = *(const uint4*)(hp + 2048);   // H tile 2j+1 (4096 B)
    Ha_o[1].u = *(const uint4*)(hp + 2304);   // (4608 B)
    Ha_o[2].u = *(const uint4*)(hp + 3072);   // (6144 B)
    Ha_o[3].u = *(const uint4*)(hp + 3328);   // (6656 B)
    F0.u = *(const uint4*)(fp + 512);         // F tile 2j+2 (1024 B)
    body(Ha_e, F1, true);                     // tile 2j, S <- scores(2j+1)
    hp += 4096;                               // -> base of tile 2j+2
    Ha_e[0].u = *(const uint4*)(hp);          // H tile 2j+2 (0 B)
    Ha_e[1].u = *(const uint4*)(hp + 256);    // (512 B)
    Ha_e[2].u = *(const uint4*)(hp + 1024);   // (2048 B)
    Ha_e[3].u = *(const uint4*)(hp + 1280);   // (2560 B)
    F1.u = *(const uint4*)(fp + 768);         // F tile 2j+3 (1536 B)
    body(Ha_o, F0, true);                     // tile 2j+1, S <- scores(2j+2)
    fp += 512;
  }
  // tail: hp = base of tile 30; Ha_e holds H(30), F1 holds F(31)
  Ha_o[0].u = *(const uint4*)(hp + 2048);     // H tile 31
  Ha_o[1].u = *(const uint4*)(hp + 2304);
  Ha_o[2].u = *(const uint4*)(hp + 3072);
  Ha_o[3].u = *(const uint4*)(hp + 3328);
  body(Ha_e, F1, true);                       // tile 30, S <- scores(31)
  body(Ha_o, F1, false);                      // tile 31 (no produce)

  // ---- epilogue: 2 phases (tile0 = O00/O01, tile1 = O10/O11) ----
  float lp0 = lp0v.x + lp0v.y;
  float lp1 = lp1v.x + lp1v.y;
  lp0 += __shfl_xor(lp0, 32, 64);
  lp1 += __shfl_xor(lp1, 32, 64);
  if (hh == 0) {
    lred[wave][ml] = lp0;
    lred[wave][32 + ml] = lp1;
  }

  const float gam = gamma[0];

  auto stash = [&](const f32x16& Oa, const f32x16& Ob) {
#pragma unroll
    for (int r = 0; r < 8; ++r) {
      const int c0 = ((2 * r) & 3) + 8 * (r >> 1) + 4 * hh;
      *(unsigned*)&Opart[wave][ml][c0] = packbf(Oa[2 * r], Oa[2 * r + 1]);
      *(unsigned*)&Opart[wave][ml][c0 + 32] = packbf(Ob[2 * r], Ob[2 * r + 1]);
    }
  };
  auto drain = [&](int p) {
    const int c = tid >> 2;
    const int m8 = (tid & 3) << 3;
    float a[8];
#pragma unroll
    for (int j = 0; j < 8; ++j) a[j] = 0.f;
#pragma unroll
    for (int w = 0; w < 4; ++w)
#pragma unroll
      for (int j = 0; j < 8; ++j) a[j] += b2f(Opart[w][m8 + j][c]);
    const f32x4 l0 = *(const f32x4*)&lsum[p * 32 + m8];
    const f32x4 l1 = *(const f32x4*)&lsum[p * 32 + m8 + 4];
    const size_t oi = (((size_t)b * 64 + c) << 12) + m0 + p * 32 + m8;
    f32x4 xo0 = *(const f32x4*)(x + oi);
    f32x4 xo1 = *(const f32x4*)(x + oi + 4);
#pragma unroll
    for (int j = 0; j < 4; ++j) {
      xo0[j] += gam / l0[j] * a[j];
      xo1[j] += gam / l1[j] * a[j + 4];
    }
    *(f32x4*)(out + oi) = xo0;
    *(f32x4*)(out + oi + 4) = xo1;
  };

  stash(O00, O01);
  __syncthreads();  // lred + phase-0 Opart visible
  if (tid < 64)
    lsum[tid] = (lred[0][tid] + lred[1][tid]) + (lred[2][tid] + lred[3][tid]);
  __syncthreads();  // lsum visible
  drain(0);
  __syncthreads();  // phase-0 reads done before overwrite
  stash(O10, O11);
  __syncthreads();  // phase-1 Opart visible
  drain(1);
}

extern "C" void kernel_launch(void* const* d_in, const int* in_sizes, int n_in,
                              void* d_out, int out_size, void* d_ws, size_t ws_size,
                              hipStream_t stream) {
  (void)in_sizes; (void)n_in; (void)out_size; (void)ws_size;
  const float* x = (const float*)d_in[0];
  const float* wq = (const float*)d_in[1];
  const float* wk = (const float*)d_in[2];
  const float* wv = (const float*)d_in[3];
  const float* gamma = (const float*)d_in[4];
  float* out = (float*)d_out;

  // workspace: f_t [8][4096][8] bf16, g_t same, h_blk [8][512][64][8] bf16
  unsigned short* f_t = (unsigned short*)d_ws;
  unsigned short* g_t = f_t + (size_t)8 * 4096 * 8;
  unsigned short* h = g_t + (size_t)8 * 4096 * 8;

  proj_kernel<<<512, 256, 0, stream>>>(x, wq, wk, wv, f_t, g_t, h);
  attn_kernel<<<512, 256, 0, stream>>>(f_t, g_t, h, x, gamma, out);
}